// Round 5
// baseline (269.964 us; speedup 1.0000x reference)
//
#include <hip/hip_runtime.h>
#include <cstdint>
#include <cstddef>
#include <math.h>

typedef _Float16 half8 __attribute__((ext_vector_type(8)));
typedef _Float16 half4 __attribute__((ext_vector_type(4)));
typedef float f32x4 __attribute__((ext_vector_type(4)));

#define NB  2
#define NT  2048
#define NC  1024
#define NH  16
#define ND  64

__device__ __forceinline__ void gload_lds16(const _Float16* g, _Float16* l) {
  __builtin_amdgcn_global_load_lds((const __attribute__((address_space(1))) void*)g,
                                   (__attribute__((address_space(3))) void*)l, 16, 0, 0);
}

// ---------------- convert x -> fp16 ----------------
__global__ void k_cvt_x(const float* __restrict__ x, _Float16* __restrict__ xh) {
  const int n4 = (4096 * 1024) / 4;
  int i = blockIdx.x * 256 + threadIdx.x;
  for (; i < n4; i += 2048 * 256) {
    float4 v = ((const float4*)x)[i];
    half4 h = { (_Float16)v.x, (_Float16)v.y, (_Float16)v.z, (_Float16)v.w };
    ((half4*)xh)[i] = h;
  }
}

// ------------- transpose+convert W (1024x1024) -> WT[n][k] fp16 -------------
__global__ void k_tw(const float* __restrict__ W0, const float* __restrict__ W1,
                     const float* __restrict__ W2, const float* __restrict__ W3,
                     _Float16* __restrict__ WT) {
  const float* W = (blockIdx.z == 0) ? W0 : (blockIdx.z == 1) ? W1 : (blockIdx.z == 2) ? W2 : W3;
  _Float16* out = WT + ((size_t)blockIdx.z << 20);
  __shared__ float t[32][33];
  const int x0 = blockIdx.x * 32;  // n
  const int y0 = blockIdx.y * 32;  // k
  const int tx = threadIdx.x, ty = threadIdx.y;  // (32,8)
#pragma unroll
  for (int r = 0; r < 4; ++r)
    t[ty + 8 * r][tx] = W[(size_t)(y0 + ty + 8 * r) * 1024 + x0 + tx];
  __syncthreads();
#pragma unroll
  for (int r = 0; r < 4; ++r)
    out[(size_t)(x0 + ty + 8 * r) * 1024 + y0 + tx] = (_Float16)t[tx][ty + 8 * r];
}

// ---------------- shared GEMM mainloop: C(128x128) = A(128xK) * B^T(128xK) ----------------
__device__ __forceinline__ void gemm_mainloop(const _Float16* __restrict__ A,
                                              const _Float16* __restrict__ Bmat,
                                              int m0, int n0,
                                              _Float16* As, _Float16* Bs,
                                              f32x4 acc[4][4]) {
  const int tid = threadIdx.x;
  const int lane = tid & 63;
  const int wid = tid >> 6;
  const int wm = wid >> 1, wn = wid & 1;
  const int c16 = lane & 15, rg = lane >> 4;

  for (int k0 = 0; k0 < 1024; k0 += 64) {
    __syncthreads();
#pragma unroll
    for (int i = 0; i < 4; ++i) {
      int e = (i * 256 + tid) * 8;       // element index within 128x64 tile
      int row = e >> 6;                  // 0..127
      int chunk = (e & 63) >> 3;         // 0..7 (16B chunk)
      int scol = ((chunk ^ (row & 7)) << 3);  // source-side swizzle (involution)
      gload_lds16(A + (size_t)(m0 + row) * 1024 + k0 + scol,
                  As + (size_t)(i * 256 + (wid << 6)) * 8);
      gload_lds16(Bmat + (size_t)(n0 + row) * 1024 + k0 + scol,
                  Bs + (size_t)(i * 256 + (wid << 6)) * 8);
    }
    __syncthreads();
#pragma unroll
    for (int kk = 0; kk < 2; ++kk) {
      half8 af[4], bfr[4];
#pragma unroll
      for (int mi = 0; mi < 4; ++mi) {
        int row = (wm << 6) + (mi << 4) + c16;
        int chunk = (kk << 2) + rg;
        af[mi] = *(const half8*)&As[(row << 6) + ((chunk ^ (row & 7)) << 3)];
      }
#pragma unroll
      for (int ni = 0; ni < 4; ++ni) {
        int row = (wn << 6) + (ni << 4) + c16;
        int chunk = (kk << 2) + rg;
        bfr[ni] = *(const half8*)&Bs[(row << 6) + ((chunk ^ (row & 7)) << 3)];
      }
#pragma unroll
      for (int mi = 0; mi < 4; ++mi)
#pragma unroll
        for (int ni = 0; ni < 4; ++ni)
          acc[mi][ni] = __builtin_amdgcn_mfma_f32_16x16x32_f16(af[mi], bfr[ni], acc[mi][ni], 0, 0, 0);
    }
  }
}

// ---------------- QKV GEMM + bias + RoPE + scatter ----------------
// Q,K -> [bh][t][d] (Q pre-scaled by 1/8); V -> transposed [bh][d][t]
__global__ __launch_bounds__(256, 2) void k_qkv(const _Float16* __restrict__ xh,
                                                const _Float16* __restrict__ WT,
                                                const float* __restrict__ bq,
                                                const float* __restrict__ bk,
                                                const float* __restrict__ bv,
                                                _Float16* __restrict__ Qh,
                                                _Float16* __restrict__ Kh,
                                                _Float16* __restrict__ VT) {
  __shared__ __align__(16) _Float16 As[128 * 64];
  __shared__ __align__(16) _Float16 Bs[128 * 64];
  f32x4 acc[4][4];
#pragma unroll
  for (int i = 0; i < 4; ++i)
#pragma unroll
    for (int j = 0; j < 4; ++j) acc[i][j] = (f32x4){0.f, 0.f, 0.f, 0.f};

  const int m0 = blockIdx.y * 128;
  const int ng = blockIdx.x * 128;   // 0..3071
  const int p = ng >> 10;            // 0=q,1=k,2=v
  const int n0 = ng & 1023;
  gemm_mainloop(xh, WT + ((size_t)p << 20), m0, n0, As, Bs, acc);

  const int tid = threadIdx.x, lane = tid & 63, wid = tid >> 6;
  const int wm = wid >> 1, wn = wid & 1, c16 = lane & 15, rg = lane >> 4;
  const float* bias = (p == 0) ? bq : (p == 1) ? bk : bv;
  const int nw = n0 + (wn << 6);
  const int head = nw >> 6;          // wave's 64-col strip is exactly one head
  float bi[4];
#pragma unroll
  for (int ni = 0; ni < 4; ++ni) bi[ni] = bias[nw + (ni << 4) + c16];

  if (p == 2) {  // V: store transposed [bh][d][t], vectorized half4 over t
#pragma unroll
    for (int mi = 0; mi < 4; ++mi) {
      int m = m0 + (wm << 6) + (mi << 4) + (rg << 2);
      int b = m >> 11, t0 = m & 2047;
#pragma unroll
      for (int ni = 0; ni < 4; ++ni) {
        half4 hv;
#pragma unroll
        for (int r = 0; r < 4; ++r) hv[r] = (_Float16)(acc[mi][ni][r] + bi[ni]);
        size_t base = ((size_t)(b * NH + head) * ND + (ni << 4) + c16) * NT + t0;
        *(half4*)&VT[base] = hv;
      }
    }
    return;
  }

  _Float16* Out = (p == 0) ? Qh : Kh;
  // inv_freq[c16] = 10000^(-c16/16) = 2^(-c16 * log2(10000)/16)  (accurate exp2)
  const float invf = exp2f((float)c16 * -0.8304820237218405f);
  const float qscale = (p == 0) ? 0.125f : 1.0f;   // fold 1/sqrt(D) into Q (exact pow2)

#pragma unroll
  for (int mi = 0; mi < 4; ++mi) {
#pragma unroll
    for (int r = 0; r < 4; ++r) {
      int m = m0 + (wm << 6) + (mi << 4) + (rg << 2) + r;
      int b = m >> 11, t = m & 2047;
      float v0 = acc[mi][0][r] + bi[0];
      float v1 = acc[mi][1][r] + bi[1];
      float v2 = acc[mi][2][r] + bi[2];
      float v3 = acc[mi][3][r] + bi[3];
      {  // RoPE on d<32: pair (d, d+16)
        float th = (float)t * invf;
        float sn, cs;
        sincosf(th, &sn, &cs);   // theta reaches 2047 rad: needs libm range reduction
        float nx = v0 * cs - v1 * sn;
        v1 = v1 * cs + v0 * sn;
        v0 = nx;
      }
      size_t base = ((size_t)(b * NH + head) * NT + t) * ND;
      Out[base + 0 + c16]  = (_Float16)(v0 * qscale);
      Out[base + 16 + c16] = (_Float16)(v1 * qscale);
      Out[base + 32 + c16] = (_Float16)(v2 * qscale);
      Out[base + 48 + c16] = (_Float16)(v3 * qscale);
    }
  }
}

// ---------------- flash attention: 2048 blocks x 2 independent waves ----------------
// Block owns a 32-row q-tile; wave w handles rows tile*32 + w*16. 16 waves/CU (4/SIMD).
// LPT: long tiles at low blockIdx; XCD swizzle: 4 consecutive bh per XCD (K+V in L2).
// swapped QK^T; per-lane softmax state at q=c16; V^T direct from L2; P via swizzled LDS.
__global__ __launch_bounds__(128, 4) void k_attn(const _Float16* __restrict__ Qh,
                                                 const _Float16* __restrict__ Kh,
                                                 const _Float16* __restrict__ VT,
                                                 _Float16* __restrict__ Oh) {
  const int lin = blockIdx.x;            // 0..2047
  const int xcd = lin & 7;
  const int w = lin >> 3;                // 0..255 per XCD
  const int bh = (xcd << 2) | (w & 3);   // 4 bh per XCD -> K+V 2MB in per-XCD L2
  const int tile = 63 - (w >> 2);        // descending length: LPT dispatch order

  const int tid = threadIdx.x, lane = tid & 63, wid = tid >> 6;  // wid in {0,1}
  const int c16 = lane & 15, rg = lane >> 4;
  const size_t hb = (size_t)bh * NT * ND;
  const _Float16* Qp = Qh + hb;
  const _Float16* Kp = Kh + hb;
  const _Float16* Vp = VT + hb;

  __shared__ unsigned int P_lds[2 * 16 * 32];  // per-wave [16 q][32 u32], xor-swizzled
  const int pbase = ((wid << 4) + c16) << 5;
  const int psw = (c16 & 7) << 2;

  const int b = bh >> 4, h = bh & 15;

  const int q0 = (tile << 5) + (wid << 4);   // this wave's 16 q-rows
  const int end = q0 + 16;                   // kv must cover rows < end
  const int qg = q0 + c16;
  const int qwmin = q0;

  half8 qf0 = *(const half8*)&Qp[(size_t)qg * ND + (rg << 3)];
  half8 qf1 = *(const half8*)&Qp[(size_t)qg * ND + 32 + (rg << 3)];

  f32x4 oacc[4];
#pragma unroll
  for (int i = 0; i < 4; ++i) oacc[i] = (f32x4){0.f, 0.f, 0.f, 0.f};
  float m = -INFINITY, l = 0.f;

  half8 kA[8], kB[8], vf[8];

#define LOADK(dst, ktv) do {                                                    \
    const _Float16* kp_ = Kp + (size_t)((ktv) + c16) * ND + (rg << 3);          \
    _Pragma("unroll")                                                           \
    for (int ni = 0; ni < 4; ++ni) {                                            \
      dst[2 * ni]     = *(const half8*)(kp_ + (size_t)(ni << 4) * ND);          \
      dst[2 * ni + 1] = *(const half8*)(kp_ + (size_t)(ni << 4) * ND + 32);     \
    } } while (0)

#define LOADV(ktv) do {                                                         \
    _Pragma("unroll")                                                           \
    for (int c = 0; c < 2; ++c)                                                 \
      _Pragma("unroll")                                                         \
      for (int ni = 0; ni < 4; ++ni)                                            \
        vf[(c << 2) + ni] = *(const half8*)&Vp[(size_t)((ni << 4) + c16) * NT   \
                                               + (ktv) + (c << 5) + (rg << 3)]; \
    } while (0)

#define BODY(kb, ktc) do {                                                      \
    f32x4 s[4];                                                                 \
    _Pragma("unroll")                                                           \
    for (int ni = 0; ni < 4; ++ni) {                                            \
      f32x4 z = (f32x4){0.f, 0.f, 0.f, 0.f};                                    \
      z = __builtin_amdgcn_mfma_f32_16x16x32_f16(kb[2 * ni], qf0, z, 0, 0, 0);  \
      s[ni] = __builtin_amdgcn_mfma_f32_16x16x32_f16(kb[2 * ni + 1], qf1, z, 0, 0, 0); \
    }                                                                           \
    if ((ktc) + 63 > qwmin) {  /* causal mask needed (wave-uniform test) */     \
      _Pragma("unroll")                                                         \
      for (int ni = 0; ni < 4; ++ni)                                            \
        _Pragma("unroll")                                                       \
        for (int r = 0; r < 4; ++r) {                                           \
          int kv = (ktc) + (ni << 4) + (rg << 2) + r;                           \
          if (kv > qg) s[ni][r] = -INFINITY;                                    \
        }                                                                       \
    }                                                                           \
    float pm = -INFINITY;                                                       \
    _Pragma("unroll")                                                           \
    for (int ni = 0; ni < 4; ++ni)                                              \
      _Pragma("unroll")                                                         \
      for (int r = 0; r < 4; ++r) pm = fmaxf(pm, s[ni][r]);                     \
    pm = fmaxf(pm, __shfl_xor(pm, 16));                                         \
    pm = fmaxf(pm, __shfl_xor(pm, 32));                                         \
    if (!__all(pm <= m + 8.f)) {                                                \
      float mn = fmaxf(m, pm);                                                  \
      float corr = __expf(m - mn);                                              \
      m = mn;                                                                   \
      l *= corr;                                                                \
      float co[4];                                                              \
      _Pragma("unroll")                                                         \
      for (int r = 0; r < 4; ++r) co[r] = __shfl(corr, (rg << 2) + r);          \
      _Pragma("unroll")                                                         \
      for (int ni = 0; ni < 4; ++ni)                                            \
        _Pragma("unroll")                                                       \
        for (int r = 0; r < 4; ++r) oacc[ni][r] *= co[r];                       \
    }                                                                           \
    float ps = 0.f;                                                             \
    _Pragma("unroll")                                                           \
    for (int ni = 0; ni < 4; ++ni)                                              \
      _Pragma("unroll")                                                         \
      for (int r = 0; r < 4; ++r) {                                             \
        float pv = __expf(s[ni][r] - m);                                        \
        s[ni][r] = pv;                                                          \
        ps += pv;                                                               \
      }                                                                         \
    ps += __shfl_xor(ps, 16);                                                   \
    ps += __shfl_xor(ps, 32);                                                   \
    l += ps;                                                                    \
    _Pragma("unroll")                                                           \
    for (int ni = 0; ni < 4; ++ni) {                                            \
      uint2 wv;                                                                 \
      wv.x = __builtin_bit_cast(unsigned int, __builtin_amdgcn_cvt_pkrtz(s[ni][0], s[ni][1])); \
      wv.y = __builtin_bit_cast(unsigned int, __builtin_amdgcn_cvt_pkrtz(s[ni][2], s[ni][3])); \
      *(uint2*)&P_lds[pbase + (((ni << 3) + (rg << 1)) ^ psw)] = wv;            \
    }                                                                           \
    uint4 u0 = *(const uint4*)&P_lds[pbase + ((rg << 2) ^ psw)];                \
    uint4 u1 = *(const uint4*)&P_lds[pbase + ((16 + (rg << 2)) ^ psw)];         \
    half8 pa0 = __builtin_bit_cast(half8, u0);                                  \
    half8 pa1 = __builtin_bit_cast(half8, u1);                                  \
    _Pragma("unroll")                                                           \
    for (int ni = 0; ni < 4; ++ni)                                              \
      oacc[ni] = __builtin_amdgcn_mfma_f32_16x16x32_f16(pa0, vf[ni], oacc[ni], 0, 0, 0); \
    _Pragma("unroll")                                                           \
    for (int ni = 0; ni < 4; ++ni)                                              \
      oacc[ni] = __builtin_amdgcn_mfma_f32_16x16x32_f16(pa1, vf[4 + ni], oacc[ni], 0, 0, 0); \
  } while (0)

  // pipelined kv loop: K double-buffered (next tile's K in flight during softmax+PV)
  int kt = 0;
  LOADK(kA, 0);
  for (;;) {
    LOADV(kt);
    if (kt + 64 < end) LOADK(kB, kt + 64);
    BODY(kA, kt);
    kt += 64;
    if (kt >= end) break;
    LOADV(kt);
    if (kt + 64 < end) LOADK(kA, kt + 64);
    BODY(kB, kt);
    kt += 64;
    if (kt >= end) break;
  }
#undef LOADK
#undef LOADV
#undef BODY

  // epilogue: normalize, store O as [b*T+t][h*64+d] fp16
  float il = 1.f / l;
#pragma unroll
  for (int r = 0; r < 4; ++r) {
    float ilo = __shfl(il, (rg << 2) + r);
    int q = q0 + (rg << 2) + r;
    size_t base = ((size_t)b * NT + q) * NC + h * ND;
#pragma unroll
    for (int ni = 0; ni < 4; ++ni)
      Oh[base + (ni << 4) + c16] = (_Float16)(oacc[ni][r] * ilo);
  }
}

// ---------------- output projection GEMM (fp32 out + bias) ----------------
__global__ __launch_bounds__(256, 2) void k_out(const _Float16* __restrict__ Oh,
                                                const _Float16* __restrict__ WoT,
                                                const float* __restrict__ bo,
                                                float* __restrict__ out) {
  __shared__ __align__(16) _Float16 As[128 * 64];
  __shared__ __align__(16) _Float16 Bs[128 * 64];
  f32x4 acc[4][4];
#pragma unroll
  for (int i = 0; i < 4; ++i)
#pragma unroll
    for (int j = 0; j < 4; ++j) acc[i][j] = (f32x4){0.f, 0.f, 0.f, 0.f};

  const int m0 = blockIdx.y * 128;
  const int n0 = blockIdx.x * 128;
  gemm_mainloop(Oh, WoT, m0, n0, As, Bs, acc);

  const int tid = threadIdx.x, lane = tid & 63, wid = tid >> 6;
  const int wm = wid >> 1, wn = wid & 1, c16 = lane & 15, rg = lane >> 4;
  float bi[4];
#pragma unroll
  for (int ni = 0; ni < 4; ++ni) bi[ni] = bo[n0 + (wn << 6) + (ni << 4) + c16];
#pragma unroll
  for (int mi = 0; mi < 4; ++mi) {
#pragma unroll
    for (int r = 0; r < 4; ++r) {
      int m = m0 + (wm << 6) + (mi << 4) + (rg << 2) + r;
#pragma unroll
      for (int ni = 0; ni < 4; ++ni) {
        int n = n0 + (wn << 6) + (ni << 4) + c16;
        out[(size_t)m * NC + n] = acc[mi][ni][r] + bi[ni];
      }
    }
  }
}

extern "C" void kernel_launch(void* const* d_in, const int* in_sizes, int n_in,
                              void* d_out, int out_size, void* d_ws, size_t ws_size,
                              hipStream_t stream) {
  const float* x  = (const float*)d_in[0];
  const float* Wq = (const float*)d_in[1];
  const float* bq = (const float*)d_in[2];
  const float* Wk = (const float*)d_in[3];
  const float* bk = (const float*)d_in[4];
  const float* Wv = (const float*)d_in[5];
  const float* bv = (const float*)d_in[6];
  const float* Wo = (const float*)d_in[7];
  const float* bo = (const float*)d_in[8];
  float* out = (float*)d_out;

  char* ws = (char*)d_ws;
  _Float16* xh = (_Float16*)ws;                       // 8 MB  [4096][1024]
  _Float16* WT = (_Float16*)(ws + (8ull << 20));      // 8 MB  [4][1024][1024] n-major
  _Float16* Qh = (_Float16*)(ws + (16ull << 20));     // 8 MB  [32][2048][64]
  _Float16* Kh = (_Float16*)(ws + (24ull << 20));     // 8 MB  [32][2048][64]
  _Float16* Vt = (_Float16*)(ws + (32ull << 20));     // 8 MB  [32][64][2048] (transposed)
  _Float16* Oh = (_Float16*)(ws + (40ull << 20));     // 8 MB  [4096][1024]

  k_cvt_x<<<2048, 256, 0, stream>>>(x, xh);
  k_tw<<<dim3(32, 32, 4), dim3(32, 8), 0, stream>>>(Wq, Wk, Wv, Wo, WT);
  k_qkv<<<dim3(24, 32), 256, 0, stream>>>(xh, WT, bq, bk, bv, Qh, Kh, Vt);
  k_attn<<<2048, 128, 0, stream>>>(Qh, Kh, Vt, Oh);
  k_out<<<dim3(8, 32), 256, 0, stream>>>(Oh, WT + (3ull << 20), bo, out);
}

// Round 6
// 207.479 us; speedup vs baseline: 1.3012x; 1.3012x over previous
//
#include <hip/hip_runtime.h>
#include <cstdint>
#include <cstddef>
#include <math.h>

typedef _Float16 half8 __attribute__((ext_vector_type(8)));
typedef _Float16 half4 __attribute__((ext_vector_type(4)));
typedef float f32x4 __attribute__((ext_vector_type(4)));

#define NB  2
#define NT  2048
#define NC  1024
#define NH  16
#define ND  64

__device__ __forceinline__ void gload_lds16(const _Float16* g, _Float16* l) {
  __builtin_amdgcn_global_load_lds((const __attribute__((address_space(1))) void*)g,
                                   (__attribute__((address_space(3))) void*)l, 16, 0, 0);
}

// ---------------- convert x -> fp16 ----------------
__global__ void k_cvt_x(const float* __restrict__ x, _Float16* __restrict__ xh) {
  const int n4 = (4096 * 1024) / 4;
  int i = blockIdx.x * 256 + threadIdx.x;
  for (; i < n4; i += 2048 * 256) {
    float4 v = ((const float4*)x)[i];
    half4 h = { (_Float16)v.x, (_Float16)v.y, (_Float16)v.z, (_Float16)v.w };
    ((half4*)xh)[i] = h;
  }
}

// ------------- transpose+convert W (1024x1024) -> WT[n][k] fp16 -------------
__global__ void k_tw(const float* __restrict__ W0, const float* __restrict__ W1,
                     const float* __restrict__ W2, const float* __restrict__ W3,
                     _Float16* __restrict__ WT) {
  const float* W = (blockIdx.z == 0) ? W0 : (blockIdx.z == 1) ? W1 : (blockIdx.z == 2) ? W2 : W3;
  _Float16* out = WT + ((size_t)blockIdx.z << 20);
  __shared__ float t[32][33];
  const int x0 = blockIdx.x * 32;  // n
  const int y0 = blockIdx.y * 32;  // k
  const int tx = threadIdx.x, ty = threadIdx.y;  // (32,8)
#pragma unroll
  for (int r = 0; r < 4; ++r)
    t[ty + 8 * r][tx] = W[(size_t)(y0 + ty + 8 * r) * 1024 + x0 + tx];
  __syncthreads();
#pragma unroll
  for (int r = 0; r < 4; ++r)
    out[(size_t)(x0 + ty + 8 * r) * 1024 + y0 + tx] = (_Float16)t[tx][ty + 8 * r];
}

// ---------------- shared GEMM mainloop: C(128x128) = A(128xK) * B^T(128xK) ----------------
__device__ __forceinline__ void gemm_mainloop(const _Float16* __restrict__ A,
                                              const _Float16* __restrict__ Bmat,
                                              int m0, int n0,
                                              _Float16* As, _Float16* Bs,
                                              f32x4 acc[4][4]) {
  const int tid = threadIdx.x;
  const int lane = tid & 63;
  const int wid = tid >> 6;
  const int wm = wid >> 1, wn = wid & 1;
  const int c16 = lane & 15, rg = lane >> 4;

  for (int k0 = 0; k0 < 1024; k0 += 64) {
    __syncthreads();
#pragma unroll
    for (int i = 0; i < 4; ++i) {
      int e = (i * 256 + tid) * 8;       // element index within 128x64 tile
      int row = e >> 6;                  // 0..127
      int chunk = (e & 63) >> 3;         // 0..7 (16B chunk)
      int scol = ((chunk ^ (row & 7)) << 3);  // source-side swizzle (involution)
      gload_lds16(A + (size_t)(m0 + row) * 1024 + k0 + scol,
                  As + (size_t)(i * 256 + (wid << 6)) * 8);
      gload_lds16(Bmat + (size_t)(n0 + row) * 1024 + k0 + scol,
                  Bs + (size_t)(i * 256 + (wid << 6)) * 8);
    }
    __syncthreads();
#pragma unroll
    for (int kk = 0; kk < 2; ++kk) {
      half8 af[4], bfr[4];
#pragma unroll
      for (int mi = 0; mi < 4; ++mi) {
        int row = (wm << 6) + (mi << 4) + c16;
        int chunk = (kk << 2) + rg;
        af[mi] = *(const half8*)&As[(row << 6) + ((chunk ^ (row & 7)) << 3)];
      }
#pragma unroll
      for (int ni = 0; ni < 4; ++ni) {
        int row = (wn << 6) + (ni << 4) + c16;
        int chunk = (kk << 2) + rg;
        bfr[ni] = *(const half8*)&Bs[(row << 6) + ((chunk ^ (row & 7)) << 3)];
      }
#pragma unroll
      for (int mi = 0; mi < 4; ++mi)
#pragma unroll
        for (int ni = 0; ni < 4; ++ni)
          acc[mi][ni] = __builtin_amdgcn_mfma_f32_16x16x32_f16(af[mi], bfr[ni], acc[mi][ni], 0, 0, 0);
    }
  }
}

// ---------------- QKV GEMM + bias + RoPE + scatter ----------------
// Q,K -> [bh][t][d] (Q pre-scaled by 1/8); V -> transposed [bh][d][t]
__global__ __launch_bounds__(256, 2) void k_qkv(const _Float16* __restrict__ xh,
                                                const _Float16* __restrict__ WT,
                                                const float* __restrict__ bq,
                                                const float* __restrict__ bk,
                                                const float* __restrict__ bv,
                                                _Float16* __restrict__ Qh,
                                                _Float16* __restrict__ Kh,
                                                _Float16* __restrict__ VT) {
  __shared__ __align__(16) _Float16 As[128 * 64];
  __shared__ __align__(16) _Float16 Bs[128 * 64];
  f32x4 acc[4][4];
#pragma unroll
  for (int i = 0; i < 4; ++i)
#pragma unroll
    for (int j = 0; j < 4; ++j) acc[i][j] = (f32x4){0.f, 0.f, 0.f, 0.f};

  const int m0 = blockIdx.y * 128;
  const int ng = blockIdx.x * 128;   // 0..3071
  const int p = ng >> 10;            // 0=q,1=k,2=v
  const int n0 = ng & 1023;
  gemm_mainloop(xh, WT + ((size_t)p << 20), m0, n0, As, Bs, acc);

  const int tid = threadIdx.x, lane = tid & 63, wid = tid >> 6;
  const int wm = wid >> 1, wn = wid & 1, c16 = lane & 15, rg = lane >> 4;
  const float* bias = (p == 0) ? bq : (p == 1) ? bk : bv;
  const int nw = n0 + (wn << 6);
  const int head = nw >> 6;          // wave's 64-col strip is exactly one head
  float bi[4];
#pragma unroll
  for (int ni = 0; ni < 4; ++ni) bi[ni] = bias[nw + (ni << 4) + c16];

  if (p == 2) {  // V: store transposed [bh][d][t], vectorized half4 over t
#pragma unroll
    for (int mi = 0; mi < 4; ++mi) {
      int m = m0 + (wm << 6) + (mi << 4) + (rg << 2);
      int b = m >> 11, t0 = m & 2047;
#pragma unroll
      for (int ni = 0; ni < 4; ++ni) {
        half4 hv;
#pragma unroll
        for (int r = 0; r < 4; ++r) hv[r] = (_Float16)(acc[mi][ni][r] + bi[ni]);
        size_t base = ((size_t)(b * NH + head) * ND + (ni << 4) + c16) * NT + t0;
        *(half4*)&VT[base] = hv;
      }
    }
    return;
  }

  _Float16* Out = (p == 0) ? Qh : Kh;
  // inv_freq[c16] = 10000^(-c16/16) = 2^(-c16 * log2(10000)/16)  (accurate exp2)
  const float invf = exp2f((float)c16 * -0.8304820237218405f);
  const float qscale = (p == 0) ? 0.125f : 1.0f;   // fold 1/sqrt(D) into Q (exact pow2)

#pragma unroll
  for (int mi = 0; mi < 4; ++mi) {
#pragma unroll
    for (int r = 0; r < 4; ++r) {
      int m = m0 + (wm << 6) + (mi << 4) + (rg << 2) + r;
      int b = m >> 11, t = m & 2047;
      float v0 = acc[mi][0][r] + bi[0];
      float v1 = acc[mi][1][r] + bi[1];
      float v2 = acc[mi][2][r] + bi[2];
      float v3 = acc[mi][3][r] + bi[3];
      {  // RoPE on d<32: pair (d, d+16)
        float th = (float)t * invf;
        float sn, cs;
        sincosf(th, &sn, &cs);   // theta reaches 2047 rad: needs libm range reduction
        float nx = v0 * cs - v1 * sn;
        v1 = v1 * cs + v0 * sn;
        v0 = nx;
      }
      size_t base = ((size_t)(b * NH + head) * NT + t) * ND;
      Out[base + 0 + c16]  = (_Float16)(v0 * qscale);
      Out[base + 16 + c16] = (_Float16)(v1 * qscale);
      Out[base + 32 + c16] = (_Float16)(v2 * qscale);
      Out[base + 48 + c16] = (_Float16)(v3 * qscale);
    }
  }
}

// ---------------- flash attention: 1024 blocks x 4 waves, KVBLK=32, K-dbuf ----------------
// Block = one 64-row q-tile (4 waves x 16 rows, shared kv loop -> L1 line sharing).
// 4 blocks/CU -> 16 waves/CU (4/SIMD). KVBLK=32 keeps dbuf regs small (~110 VGPR) so the
// compiler can keep the prefetch alive. Descending tile length within XCD for balance.
__global__ __launch_bounds__(256, 4) void k_attn(const _Float16* __restrict__ Qh,
                                                 const _Float16* __restrict__ Kh,
                                                 const _Float16* __restrict__ VT,
                                                 _Float16* __restrict__ Oh) {
  const int lin = blockIdx.x;            // 0..1023
  const int xcd = lin & 7;
  const int w = lin >> 3;                // 0..127 per XCD
  const int bh = (xcd << 2) | (w & 3);   // 4 bh per XCD -> K+V 2MB in per-XCD L2
  const int tile = 31 - (w >> 2);        // descending length (longest first per XCD)

  const int tid = threadIdx.x, lane = tid & 63, wid = tid >> 6;  // wid 0..3
  const int c16 = lane & 15, rg = lane >> 4;
  const size_t hb = (size_t)bh * NT * ND;
  const _Float16* Qp = Qh + hb;
  const _Float16* Kp = Kh + hb;
  const _Float16* Vp = VT + hb;

  __shared__ unsigned int P_lds[4 * 16 * 32];  // per-wave [16 q][32 u32], xor-swizzled
  const int pbase = ((wid << 4) + c16) << 5;
  const int psw = (c16 & 7) << 2;

  const int b = bh >> 4, h = bh & 15;

  const int q0 = (tile << 6) + (wid << 4);   // this wave's 16 q-rows
  const int end = (tile << 6) + 64;          // block-shared kv extent
  const int qg = q0 + c16;

  half8 qf0 = *(const half8*)&Qp[(size_t)qg * ND + (rg << 3)];
  half8 qf1 = *(const half8*)&Qp[(size_t)qg * ND + 32 + (rg << 3)];

  f32x4 oacc[4];
#pragma unroll
  for (int i = 0; i < 4; ++i) oacc[i] = (f32x4){0.f, 0.f, 0.f, 0.f};
  float m = -INFINITY, l = 0.f;

  half8 kA[4], kB[4], vf[4];

// K fragments for a 32-row kv tile: kf[2*ni+h] = K[(kt+ni*16+c16)][h*32 + rg*8]
#define LOADK(dst, ktv) do {                                                    \
    const _Float16* kp_ = Kp + (size_t)((ktv) + c16) * ND + (rg << 3);          \
    dst[0] = *(const half8*)(kp_);                                              \
    dst[1] = *(const half8*)(kp_ + 32);                                         \
    dst[2] = *(const half8*)(kp_ + (size_t)(16) * ND);                          \
    dst[3] = *(const half8*)(kp_ + (size_t)(16) * ND + 32);                     \
  } while (0)

// V^T fragments: vf[ni] = VT[(ni*16+c16)][kt + rg*8]  (k dim = 32 kv)
#define LOADV(ktv) do {                                                         \
    _Pragma("unroll")                                                           \
    for (int ni = 0; ni < 4; ++ni)                                              \
      vf[ni] = *(const half8*)&Vp[(size_t)((ni << 4) + c16) * NT + (ktv) + (rg << 3)]; \
  } while (0)

#define BODY(kb, ktc) do {                                                      \
    f32x4 s[2];                                                                 \
    _Pragma("unroll")                                                           \
    for (int ni = 0; ni < 2; ++ni) {                                            \
      f32x4 z = (f32x4){0.f, 0.f, 0.f, 0.f};                                    \
      z = __builtin_amdgcn_mfma_f32_16x16x32_f16(kb[2 * ni], qf0, z, 0, 0, 0);  \
      s[ni] = __builtin_amdgcn_mfma_f32_16x16x32_f16(kb[2 * ni + 1], qf1, z, 0, 0, 0); \
    }                                                                           \
    if ((ktc) + 31 > q0) {  /* causal mask needed (wave-uniform test) */        \
      _Pragma("unroll")                                                         \
      for (int ni = 0; ni < 2; ++ni)                                            \
        _Pragma("unroll")                                                       \
        for (int r = 0; r < 4; ++r) {                                           \
          int kv = (ktc) + (ni << 4) + (rg << 2) + r;                           \
          if (kv > qg) s[ni][r] = -INFINITY;                                    \
        }                                                                       \
    }                                                                           \
    float pm = -INFINITY;                                                       \
    _Pragma("unroll")                                                           \
    for (int ni = 0; ni < 2; ++ni)                                              \
      _Pragma("unroll")                                                         \
      for (int r = 0; r < 4; ++r) pm = fmaxf(pm, s[ni][r]);                     \
    pm = fmaxf(pm, __shfl_xor(pm, 16));                                         \
    pm = fmaxf(pm, __shfl_xor(pm, 32));                                         \
    if (!__all(pm <= m + 8.f)) {                                                \
      float mn = fmaxf(m, pm);                                                  \
      float corr = __expf(m - mn);                                              \
      m = mn;                                                                   \
      l *= corr;                                                                \
      float co[4];                                                              \
      _Pragma("unroll")                                                         \
      for (int r = 0; r < 4; ++r) co[r] = __shfl(corr, (rg << 2) + r);          \
      _Pragma("unroll")                                                         \
      for (int ni = 0; ni < 4; ++ni)                                            \
        _Pragma("unroll")                                                       \
        for (int r = 0; r < 4; ++r) oacc[ni][r] *= co[r];                       \
    }                                                                           \
    float ps = 0.f;                                                             \
    _Pragma("unroll")                                                           \
    for (int ni = 0; ni < 2; ++ni)                                              \
      _Pragma("unroll")                                                         \
      for (int r = 0; r < 4; ++r) {                                             \
        float pv = __expf(s[ni][r] - m);                                        \
        s[ni][r] = pv;                                                          \
        ps += pv;                                                               \
      }                                                                         \
    ps += __shfl_xor(ps, 16);                                                   \
    ps += __shfl_xor(ps, 32);                                                   \
    l += ps;                                                                    \
    _Pragma("unroll")                                                           \
    for (int ni = 0; ni < 2; ++ni) {                                            \
      uint2 wv;                                                                 \
      wv.x = __builtin_bit_cast(unsigned int, __builtin_amdgcn_cvt_pkrtz(s[ni][0], s[ni][1])); \
      wv.y = __builtin_bit_cast(unsigned int, __builtin_amdgcn_cvt_pkrtz(s[ni][2], s[ni][3])); \
      *(uint2*)&P_lds[pbase + (((ni << 3) + (rg << 1)) ^ psw)] = wv;            \
    }                                                                           \
    uint4 u0 = *(const uint4*)&P_lds[pbase + ((rg << 2) ^ psw)];                \
    half8 pa0 = __builtin_bit_cast(half8, u0);                                  \
    _Pragma("unroll")                                                           \
    for (int ni = 0; ni < 4; ++ni)                                              \
      oacc[ni] = __builtin_amdgcn_mfma_f32_16x16x32_f16(pa0, vf[ni], oacc[ni], 0, 0, 0); \
  } while (0)

  // pipelined kv loop, KVBLK=32: K double-buffered, V issued at iter top
  int kt = 0;
  LOADK(kA, 0);
  for (;;) {
    LOADV(kt);
    if (kt + 32 < end) LOADK(kB, kt + 32);
    BODY(kA, kt);
    kt += 32;
    if (kt >= end) break;
    LOADV(kt);
    if (kt + 32 < end) LOADK(kA, kt + 32);
    BODY(kB, kt);
    kt += 32;
    if (kt >= end) break;
  }
#undef LOADK
#undef LOADV
#undef BODY

  // epilogue: normalize, store O as [b*T+t][h*64+d] fp16
  float il = 1.f / l;
#pragma unroll
  for (int r = 0; r < 4; ++r) {
    float ilo = __shfl(il, (rg << 2) + r);
    int q = q0 + (rg << 2) + r;
    size_t base = ((size_t)b * NT + q) * NC + h * ND;
#pragma unroll
    for (int ni = 0; ni < 4; ++ni)
      Oh[base + (ni << 4) + c16] = (_Float16)(oacc[ni][r] * ilo);
  }
}

// ---------------- output projection GEMM (fp32 out + bias) ----------------
__global__ __launch_bounds__(256, 2) void k_out(const _Float16* __restrict__ Oh,
                                                const _Float16* __restrict__ WoT,
                                                const float* __restrict__ bo,
                                                float* __restrict__ out) {
  __shared__ __align__(16) _Float16 As[128 * 64];
  __shared__ __align__(16) _Float16 Bs[128 * 64];
  f32x4 acc[4][4];
#pragma unroll
  for (int i = 0; i < 4; ++i)
#pragma unroll
    for (int j = 0; j < 4; ++j) acc[i][j] = (f32x4){0.f, 0.f, 0.f, 0.f};

  const int m0 = blockIdx.y * 128;
  const int n0 = blockIdx.x * 128;
  gemm_mainloop(Oh, WoT, m0, n0, As, Bs, acc);

  const int tid = threadIdx.x, lane = tid & 63, wid = tid >> 6;
  const int wm = wid >> 1, wn = wid & 1, c16 = lane & 15, rg = lane >> 4;
  float bi[4];
#pragma unroll
  for (int ni = 0; ni < 4; ++ni) bi[ni] = bo[n0 + (wn << 6) + (ni << 4) + c16];
#pragma unroll
  for (int mi = 0; mi < 4; ++mi) {
#pragma unroll
    for (int r = 0; r < 4; ++r) {
      int m = m0 + (wm << 6) + (mi << 4) + (rg << 2) + r;
#pragma unroll
      for (int ni = 0; ni < 4; ++ni) {
        int n = n0 + (wn << 6) + (ni << 4) + c16;
        out[(size_t)m * NC + n] = acc[mi][ni][r] + bi[ni];
      }
    }
  }
}

extern "C" void kernel_launch(void* const* d_in, const int* in_sizes, int n_in,
                              void* d_out, int out_size, void* d_ws, size_t ws_size,
                              hipStream_t stream) {
  const float* x  = (const float*)d_in[0];
  const float* Wq = (const float*)d_in[1];
  const float* bq = (const float*)d_in[2];
  const float* Wk = (const float*)d_in[3];
  const float* bk = (const float*)d_in[4];
  const float* Wv = (const float*)d_in[5];
  const float* bv = (const float*)d_in[6];
  const float* Wo = (const float*)d_in[7];
  const float* bo = (const float*)d_in[8];
  float* out = (float*)d_out;

  char* ws = (char*)d_ws;
  _Float16* xh = (_Float16*)ws;                       // 8 MB  [4096][1024]
  _Float16* WT = (_Float16*)(ws + (8ull << 20));      // 8 MB  [4][1024][1024] n-major
  _Float16* Qh = (_Float16*)(ws + (16ull << 20));     // 8 MB  [32][2048][64]
  _Float16* Kh = (_Float16*)(ws + (24ull << 20));     // 8 MB  [32][2048][64]
  _Float16* Vt = (_Float16*)(ws + (32ull << 20));     // 8 MB  [32][64][2048] (transposed)
  _Float16* Oh = (_Float16*)(ws + (40ull << 20));     // 8 MB  [4096][1024]

  k_cvt_x<<<2048, 256, 0, stream>>>(x, xh);
  k_tw<<<dim3(32, 32, 4), dim3(32, 8), 0, stream>>>(Wq, Wk, Wv, Wo, WT);
  k_qkv<<<dim3(24, 32), 256, 0, stream>>>(xh, WT, bq, bk, bv, Qh, Kh, Vt);
  k_attn<<<1024, 256, 0, stream>>>(Qh, Kh, Vt, Oh);
  k_out<<<dim3(8, 32), 256, 0, stream>>>(Oh, WT + (3ull << 20), bo, out);
}

// Round 7
// 152.135 us; speedup vs baseline: 1.7745x; 1.3638x over previous
//
#include <hip/hip_runtime.h>
#include <cstdint>
#include <cstddef>
#include <math.h>

typedef _Float16 half8 __attribute__((ext_vector_type(8)));
typedef _Float16 half4 __attribute__((ext_vector_type(4)));
typedef float f32x4 __attribute__((ext_vector_type(4)));
typedef float f32x16 __attribute__((ext_vector_type(16)));

#define NB  2
#define NT  2048
#define NC  1024
#define NH  16
#define ND  64

__device__ __forceinline__ void gload_lds16(const _Float16* g, _Float16* l) {
  __builtin_amdgcn_global_load_lds((const __attribute__((address_space(1))) void*)g,
                                   (__attribute__((address_space(3))) void*)l, 16, 0, 0);
}

// ---------------- convert x -> fp16 ----------------
__global__ void k_cvt_x(const float* __restrict__ x, _Float16* __restrict__ xh) {
  const int n4 = (4096 * 1024) / 4;
  int i = blockIdx.x * 256 + threadIdx.x;
  for (; i < n4; i += 2048 * 256) {
    float4 v = ((const float4*)x)[i];
    half4 h = { (_Float16)v.x, (_Float16)v.y, (_Float16)v.z, (_Float16)v.w };
    ((half4*)xh)[i] = h;
  }
}

// ------------- transpose+convert W (1024x1024) -> WT[n][k] fp16 -------------
__global__ void k_tw(const float* __restrict__ W0, const float* __restrict__ W1,
                     const float* __restrict__ W2, const float* __restrict__ W3,
                     _Float16* __restrict__ WT) {
  const float* W = (blockIdx.z == 0) ? W0 : (blockIdx.z == 1) ? W1 : (blockIdx.z == 2) ? W2 : W3;
  _Float16* out = WT + ((size_t)blockIdx.z << 20);
  __shared__ float t[32][33];
  const int x0 = blockIdx.x * 32;  // n
  const int y0 = blockIdx.y * 32;  // k
  const int tx = threadIdx.x, ty = threadIdx.y;  // (32,8)
#pragma unroll
  for (int r = 0; r < 4; ++r)
    t[ty + 8 * r][tx] = W[(size_t)(y0 + ty + 8 * r) * 1024 + x0 + tx];
  __syncthreads();
#pragma unroll
  for (int r = 0; r < 4; ++r)
    out[(size_t)(x0 + ty + 8 * r) * 1024 + y0 + tx] = (_Float16)t[tx][ty + 8 * r];
}

// ---------------- shared GEMM mainloop: C(128x128) = A(128xK) * B^T(128xK) ----------------
__device__ __forceinline__ void gemm_mainloop(const _Float16* __restrict__ A,
                                              const _Float16* __restrict__ Bmat,
                                              int m0, int n0,
                                              _Float16* As, _Float16* Bs,
                                              f32x4 acc[4][4]) {
  const int tid = threadIdx.x;
  const int lane = tid & 63;
  const int wid = tid >> 6;
  const int wm = wid >> 1, wn = wid & 1;
  const int c16 = lane & 15, rg = lane >> 4;

  for (int k0 = 0; k0 < 1024; k0 += 64) {
    __syncthreads();
#pragma unroll
    for (int i = 0; i < 4; ++i) {
      int e = (i * 256 + tid) * 8;       // element index within 128x64 tile
      int row = e >> 6;                  // 0..127
      int chunk = (e & 63) >> 3;         // 0..7 (16B chunk)
      int scol = ((chunk ^ (row & 7)) << 3);  // source-side swizzle (involution)
      gload_lds16(A + (size_t)(m0 + row) * 1024 + k0 + scol,
                  As + (size_t)(i * 256 + (wid << 6)) * 8);
      gload_lds16(Bmat + (size_t)(n0 + row) * 1024 + k0 + scol,
                  Bs + (size_t)(i * 256 + (wid << 6)) * 8);
    }
    __syncthreads();
#pragma unroll
    for (int kk = 0; kk < 2; ++kk) {
      half8 af[4], bfr[4];
#pragma unroll
      for (int mi = 0; mi < 4; ++mi) {
        int row = (wm << 6) + (mi << 4) + c16;
        int chunk = (kk << 2) + rg;
        af[mi] = *(const half8*)&As[(row << 6) + ((chunk ^ (row & 7)) << 3)];
      }
#pragma unroll
      for (int ni = 0; ni < 4; ++ni) {
        int row = (wn << 6) + (ni << 4) + c16;
        int chunk = (kk << 2) + rg;
        bfr[ni] = *(const half8*)&Bs[(row << 6) + ((chunk ^ (row & 7)) << 3)];
      }
#pragma unroll
      for (int mi = 0; mi < 4; ++mi)
#pragma unroll
        for (int ni = 0; ni < 4; ++ni)
          acc[mi][ni] = __builtin_amdgcn_mfma_f32_16x16x32_f16(af[mi], bfr[ni], acc[mi][ni], 0, 0, 0);
    }
  }
}

// ---------------- QKV GEMM + bias + RoPE + scatter ----------------
// Q -> [bh][t][d] scaled by (1/8)*log2(e) (exp2-domain softmax); K -> [bh][t][d];
// V -> transposed [bh][d][t]
__global__ __launch_bounds__(256, 2) void k_qkv(const _Float16* __restrict__ xh,
                                                const _Float16* __restrict__ WT,
                                                const float* __restrict__ bq,
                                                const float* __restrict__ bk,
                                                const float* __restrict__ bv,
                                                _Float16* __restrict__ Qh,
                                                _Float16* __restrict__ Kh,
                                                _Float16* __restrict__ VT) {
  __shared__ __align__(16) _Float16 As[128 * 64];
  __shared__ __align__(16) _Float16 Bs[128 * 64];
  f32x4 acc[4][4];
#pragma unroll
  for (int i = 0; i < 4; ++i)
#pragma unroll
    for (int j = 0; j < 4; ++j) acc[i][j] = (f32x4){0.f, 0.f, 0.f, 0.f};

  const int m0 = blockIdx.y * 128;
  const int ng = blockIdx.x * 128;   // 0..3071
  const int p = ng >> 10;            // 0=q,1=k,2=v
  const int n0 = ng & 1023;
  gemm_mainloop(xh, WT + ((size_t)p << 20), m0, n0, As, Bs, acc);

  const int tid = threadIdx.x, lane = tid & 63, wid = tid >> 6;
  const int wm = wid >> 1, wn = wid & 1, c16 = lane & 15, rg = lane >> 4;
  const float* bias = (p == 0) ? bq : (p == 1) ? bk : bv;
  const int nw = n0 + (wn << 6);
  const int head = nw >> 6;          // wave's 64-col strip is exactly one head
  float bi[4];
#pragma unroll
  for (int ni = 0; ni < 4; ++ni) bi[ni] = bias[nw + (ni << 4) + c16];

  if (p == 2) {  // V: store transposed [bh][d][t], vectorized half4 over t
#pragma unroll
    for (int mi = 0; mi < 4; ++mi) {
      int m = m0 + (wm << 6) + (mi << 4) + (rg << 2);
      int b = m >> 11, t0 = m & 2047;
#pragma unroll
      for (int ni = 0; ni < 4; ++ni) {
        half4 hv;
#pragma unroll
        for (int r = 0; r < 4; ++r) hv[r] = (_Float16)(acc[mi][ni][r] + bi[ni]);
        size_t base = ((size_t)(b * NH + head) * ND + (ni << 4) + c16) * NT + t0;
        *(half4*)&VT[base] = hv;
      }
    }
    return;
  }

  _Float16* Out = (p == 0) ? Qh : Kh;
  // inv_freq[c16] = 10000^(-c16/16) = 2^(-c16 * log2(10000)/16)  (accurate exp2)
  const float invf = exp2f((float)c16 * -0.8304820237218405f);
  // Q scale: (1/sqrt(64)) * log2(e)  -> S from MFMA is directly in exp2 domain
  const float qscale = (p == 0) ? 0.18033688011112042f : 1.0f;

#pragma unroll
  for (int mi = 0; mi < 4; ++mi) {
#pragma unroll
    for (int r = 0; r < 4; ++r) {
      int m = m0 + (wm << 6) + (mi << 4) + (rg << 2) + r;
      int b = m >> 11, t = m & 2047;
      float v0 = acc[mi][0][r] + bi[0];
      float v1 = acc[mi][1][r] + bi[1];
      float v2 = acc[mi][2][r] + bi[2];
      float v3 = acc[mi][3][r] + bi[3];
      {  // RoPE on d<32: pair (d, d+16)
        float th = (float)t * invf;
        float sn, cs;
        sincosf(th, &sn, &cs);   // theta reaches 2047 rad: needs libm range reduction
        float nx = v0 * cs - v1 * sn;
        v1 = v1 * cs + v0 * sn;
        v0 = nx;
      }
      size_t base = ((size_t)(b * NH + head) * NT + t) * ND;
      Out[base + 0 + c16]  = (_Float16)(v0 * qscale);
      Out[base + 16 + c16] = (_Float16)(v1 * qscale);
      Out[base + 32 + c16] = (_Float16)(v2 * qscale);
      Out[base + 48 + c16] = (_Float16)(v3 * qscale);
    }
  }
}

// ---------------- flash attention: 32x32 swapped-QK^T, LDS-free, in-register softmax ----
// 512 blocks x 4 waves; wave owns 32 q-rows (q = lane&31 -> softmax state per-lane).
// QK: S^T[kv][q] = mfma32x32x16(K,Q) over 4 D-chunks. C/D layout: col=lane&31=q,
// row=kv=(r&3)+8*(r>>2)+4*hi. Softmax: 15 in-lane fmax + one shfl_xor(32). P repack to
// PV B-fragments in-register (cvt_pkrtz + shfl_xor(32) + cndmask). PV: O^T[d][q] with
// A=V^T fragments from the d-major VT array. No LDS, no barriers.
__global__ __launch_bounds__(256, 2) void k_attn(const _Float16* __restrict__ Qh,
                                                 const _Float16* __restrict__ Kh,
                                                 const _Float16* __restrict__ VT,
                                                 _Float16* __restrict__ Oh) {
  const int lin = blockIdx.x;            // 0..511
  const int xcd = lin & 7;
  const int w = lin >> 3;                // 0..63 per XCD
  const int bh = (xcd << 2) | (w & 3);   // 4 bh per XCD -> K+V 2MB in per-XCD L2
  const int tile = 15 - (w >> 2);        // descending 128-row tile length (LPT)

  const int tid = threadIdx.x, lane = tid & 63, wid = tid >> 6;  // wid 0..3
  const int q31 = lane & 31, hi = lane >> 5;
  const size_t hb = (size_t)bh * NT * ND;
  const _Float16* Qp = Qh + hb;
  const _Float16* Kp = Kh + hb;
  const _Float16* Vp = VT + hb;
  const int b = bh >> 4, h = bh & 15;

  const int q0w = (tile << 7) + (wid << 5);  // this wave's 32 q-rows
  const int qg = q0w + q31;
  const int end = q0w + 32;                  // per-wave kv extent

  half8 qf[4];
#pragma unroll
  for (int c = 0; c < 4; ++c)
    qf[c] = *(const half8*)&Qp[(size_t)qg * ND + (c << 4) + (hi << 3)];

  f32x16 oacc0, oacc1;
#pragma unroll
  for (int r = 0; r < 16; ++r) { oacc0[r] = 0.f; oacc1[r] = 0.f; }
  float m = -INFINITY, l = 0.f;

  half8 kA[4], kB[4], vfr[4];

// K A-fragments (32 kv rows): dst[c] holds K[kt+q31][c*16 + hi*8 ..+8]
#define LOADK(dst, ktv) do {                                                    \
    const _Float16* kp_ = Kp + (size_t)((ktv) + q31) * ND + (hi << 3);          \
    dst[0] = *(const half8*)(kp_);                                              \
    dst[1] = *(const half8*)(kp_ + 16);                                         \
    dst[2] = *(const half8*)(kp_ + 32);                                         \
    dst[3] = *(const half8*)(kp_ + 48);                                         \
  } while (0)

// V A-fragments: vfr[dh*2+ks] = VT[dh*32+q31][kt + ks*16 + hi*8 ..+8]
#define LOADV(ktv) do {                                                         \
    _Pragma("unroll")                                                           \
    for (int dh = 0; dh < 2; ++dh)                                              \
      _Pragma("unroll")                                                         \
      for (int ks = 0; ks < 2; ++ks)                                            \
        vfr[dh * 2 + ks] = *(const half8*)&Vp[(size_t)((dh << 5) + q31) * NT    \
                                              + (ktv) + (ks << 4) + (hi << 3)]; \
  } while (0)

#define BODY(kb, ktc) do {                                                      \
    f32x16 s;                                                                   \
    _Pragma("unroll")                                                           \
    for (int r = 0; r < 16; ++r) s[r] = 0.f;                                    \
    _Pragma("unroll")                                                           \
    for (int c = 0; c < 4; ++c)                                                 \
      s = __builtin_amdgcn_mfma_f32_32x32x16_f16(kb[c], qf[c], s, 0, 0, 0);     \
    if ((ktc) + 31 > q0w) {  /* causal mask (only the last iter per wave) */    \
      int rel = qg - (ktc) - (hi << 2);                                         \
      _Pragma("unroll")                                                         \
      for (int r = 0; r < 16; ++r) {                                            \
        int crow = (r & 3) + ((r >> 2) << 3);                                   \
        if (crow > rel) s[r] = -INFINITY;                                       \
      }                                                                         \
    }                                                                           \
    float pm = s[0];                                                            \
    _Pragma("unroll")                                                           \
    for (int r = 1; r < 16; ++r) pm = fmaxf(pm, s[r]);                          \
    pm = fmaxf(pm, __shfl_xor(pm, 32));                                         \
    if (!__all(pm <= m + 11.54f)) {  /* defer-max, THR=8*log2e */               \
      float mn = fmaxf(m, pm);                                                  \
      float corr = exp2f(m - mn);                                               \
      m = mn; l *= corr;                                                        \
      _Pragma("unroll")                                                         \
      for (int r = 0; r < 16; ++r) { oacc0[r] *= corr; oacc1[r] *= corr; }      \
    }                                                                           \
    float ps = 0.f;                                                             \
    _Pragma("unroll")                                                           \
    for (int r = 0; r < 16; ++r) {                                              \
      float pv = exp2f(s[r] - m);                                               \
      s[r] = pv; ps += pv;                                                      \
    }                                                                           \
    ps += __shfl_xor(ps, 32);                                                   \
    l += ps;                                                                    \
    /* pack P to fp16 words: pwN = [P(kv even),P(kv odd)] for this lane */      \
    unsigned pw0 = __builtin_bit_cast(unsigned, __builtin_amdgcn_cvt_pkrtz(s[0], s[1]));   \
    unsigned pw1 = __builtin_bit_cast(unsigned, __builtin_amdgcn_cvt_pkrtz(s[2], s[3]));   \
    unsigned pw2 = __builtin_bit_cast(unsigned, __builtin_amdgcn_cvt_pkrtz(s[4], s[5]));   \
    unsigned pw3 = __builtin_bit_cast(unsigned, __builtin_amdgcn_cvt_pkrtz(s[6], s[7]));   \
    unsigned pw4 = __builtin_bit_cast(unsigned, __builtin_amdgcn_cvt_pkrtz(s[8], s[9]));   \
    unsigned pw5 = __builtin_bit_cast(unsigned, __builtin_amdgcn_cvt_pkrtz(s[10], s[11])); \
    unsigned pw6 = __builtin_bit_cast(unsigned, __builtin_amdgcn_cvt_pkrtz(s[12], s[13])); \
    unsigned pw7 = __builtin_bit_cast(unsigned, __builtin_amdgcn_cvt_pkrtz(s[14], s[15])); \
    /* exchange halves: lane needs the other hi-group's words for kv 4..7 (mod 16) */ \
    unsigned x0 = (unsigned)__shfl_xor((int)pw0, 32);                           \
    unsigned x1 = (unsigned)__shfl_xor((int)pw1, 32);                           \
    unsigned x2 = (unsigned)__shfl_xor((int)pw2, 32);                           \
    unsigned x3 = (unsigned)__shfl_xor((int)pw3, 32);                           \
    unsigned x4 = (unsigned)__shfl_xor((int)pw4, 32);                           \
    unsigned x5 = (unsigned)__shfl_xor((int)pw5, 32);                           \
    unsigned x6 = (unsigned)__shfl_xor((int)pw6, 32);                           \
    unsigned x7 = (unsigned)__shfl_xor((int)pw7, 32);                           \
    uint4 ua, ub;                                                               \
    ua.x = hi ? x2  : pw0;   /* ks0 word0: kv{0,1}|{8,9}   */                   \
    ua.y = hi ? x3  : pw1;   /* ks0 word1: kv{2,3}|{10,11} */                   \
    ua.z = hi ? pw2 : x0;    /* ks0 word2: kv{4,5}|{12,13} */                   \
    ua.w = hi ? pw3 : x1;    /* ks0 word3: kv{6,7}|{14,15} */                   \
    ub.x = hi ? x6  : pw4;                                                      \
    ub.y = hi ? x7  : pw5;                                                      \
    ub.z = hi ? pw6 : x4;                                                       \
    ub.w = hi ? pw7 : x5;                                                       \
    half8 pa0 = __builtin_bit_cast(half8, ua);                                  \
    half8 pa1 = __builtin_bit_cast(half8, ub);                                  \
    oacc0 = __builtin_amdgcn_mfma_f32_32x32x16_f16(vfr[0], pa0, oacc0, 0, 0, 0); \
    oacc0 = __builtin_amdgcn_mfma_f32_32x32x16_f16(vfr[1], pa1, oacc0, 0, 0, 0); \
    oacc1 = __builtin_amdgcn_mfma_f32_32x32x16_f16(vfr[2], pa0, oacc1, 0, 0, 0); \
    oacc1 = __builtin_amdgcn_mfma_f32_32x32x16_f16(vfr[3], pa1, oacc1, 0, 0, 0); \
  } while (0)

  // pipelined kv loop, KVBLK=32: K double-buffered, V issued at iter top;
  // sched_barrier pins the load issues above the compute (anti-sinking).
  int kt = 0;
  LOADK(kA, 0);
  for (;;) {
    LOADV(kt);
    if (kt + 32 < end) LOADK(kB, kt + 32);
    __builtin_amdgcn_sched_barrier(0);
    BODY(kA, kt);
    kt += 32;
    if (kt >= end) break;
    LOADV(kt);
    if (kt + 32 < end) LOADK(kA, kt + 32);
    __builtin_amdgcn_sched_barrier(0);
    BODY(kB, kt);
    kt += 32;
    if (kt >= end) break;
  }
#undef LOADK
#undef LOADV
#undef BODY

  // epilogue: normalize (per-lane l!), store O as [b*T+t][h*64+d] fp16
  float il = 1.f / l;
  size_t obase = ((size_t)b * NT + qg) * NC + h * ND;
#pragma unroll
  for (int g = 0; g < 4; ++g) {
    int d0 = (g << 3) + (hi << 2);
    half4 h4, h5;
#pragma unroll
    for (int r = 0; r < 4; ++r) {
      h4[r] = (_Float16)(oacc0[(g << 2) + r] * il);
      h5[r] = (_Float16)(oacc1[(g << 2) + r] * il);
    }
    *(half4*)&Oh[obase + d0] = h4;
    *(half4*)&Oh[obase + 32 + d0] = h5;
  }
}

// ---------------- output projection GEMM (fp32 out + bias) ----------------
__global__ __launch_bounds__(256, 2) void k_out(const _Float16* __restrict__ Oh,
                                                const _Float16* __restrict__ WoT,
                                                const float* __restrict__ bo,
                                                float* __restrict__ out) {
  __shared__ __align__(16) _Float16 As[128 * 64];
  __shared__ __align__(16) _Float16 Bs[128 * 64];
  f32x4 acc[4][4];
#pragma unroll
  for (int i = 0; i < 4; ++i)
#pragma unroll
    for (int j = 0; j < 4; ++j) acc[i][j] = (f32x4){0.f, 0.f, 0.f, 0.f};

  const int m0 = blockIdx.y * 128;
  const int n0 = blockIdx.x * 128;
  gemm_mainloop(Oh, WoT, m0, n0, As, Bs, acc);

  const int tid = threadIdx.x, lane = tid & 63, wid = tid >> 6;
  const int wm = wid >> 1, wn = wid & 1, c16 = lane & 15, rg = lane >> 4;
  float bi[4];
#pragma unroll
  for (int ni = 0; ni < 4; ++ni) bi[ni] = bo[n0 + (wn << 6) + (ni << 4) + c16];
#pragma unroll
  for (int mi = 0; mi < 4; ++mi) {
#pragma unroll
    for (int r = 0; r < 4; ++r) {
      int m = m0 + (wm << 6) + (mi << 4) + (rg << 2) + r;
#pragma unroll
      for (int ni = 0; ni < 4; ++ni) {
        int n = n0 + (wn << 6) + (ni << 4) + c16;
        out[(size_t)m * NC + n] = acc[mi][ni][r] + bi[ni];
      }
    }
  }
}

extern "C" void kernel_launch(void* const* d_in, const int* in_sizes, int n_in,
                              void* d_out, int out_size, void* d_ws, size_t ws_size,
                              hipStream_t stream) {
  const float* x  = (const float*)d_in[0];
  const float* Wq = (const float*)d_in[1];
  const float* bq = (const float*)d_in[2];
  const float* Wk = (const float*)d_in[3];
  const float* bk = (const float*)d_in[4];
  const float* Wv = (const float*)d_in[5];
  const float* bv = (const float*)d_in[6];
  const float* Wo = (const float*)d_in[7];
  const float* bo = (const float*)d_in[8];
  float* out = (float*)d_out;

  char* ws = (char*)d_ws;
  _Float16* xh = (_Float16*)ws;                       // 8 MB  [4096][1024]
  _Float16* WT = (_Float16*)(ws + (8ull << 20));      // 8 MB  [4][1024][1024] n-major
  _Float16* Qh = (_Float16*)(ws + (16ull << 20));     // 8 MB  [32][2048][64]
  _Float16* Kh = (_Float16*)(ws + (24ull << 20));     // 8 MB  [32][2048][64]
  _Float16* Vt = (_Float16*)(ws + (32ull << 20));     // 8 MB  [32][64][2048] (transposed)
  _Float16* Oh = (_Float16*)(ws + (40ull << 20));     // 8 MB  [4096][1024]

  k_cvt_x<<<2048, 256, 0, stream>>>(x, xh);
  k_tw<<<dim3(32, 32, 4), dim3(32, 8), 0, stream>>>(Wq, Wk, Wv, Wo, WT);
  k_qkv<<<dim3(24, 32), 256, 0, stream>>>(xh, WT, bq, bk, bv, Qh, Kh, Vt);
  k_attn<<<512, 256, 0, stream>>>(Qh, Kh, Vt, Oh);
  k_out<<<dim3(8, 32), 256, 0, stream>>>(Oh, WT + (3ull << 20), bo, out);
}

// Round 11
// 151.936 us; speedup vs baseline: 1.7768x; 1.0013x over previous
//
#include <hip/hip_runtime.h>
#include <cstdint>
#include <cstddef>
#include <math.h>

typedef _Float16 half8 __attribute__((ext_vector_type(8)));
typedef _Float16 half4 __attribute__((ext_vector_type(4)));
typedef float f32x4 __attribute__((ext_vector_type(4)));
typedef float f32x16 __attribute__((ext_vector_type(16)));
typedef unsigned int uint2v __attribute__((ext_vector_type(2)));

#define NB  2
#define NT  2048
#define NC  1024
#define NH  16
#define ND  64

__device__ __forceinline__ void gload_lds16(const _Float16* g, _Float16* l) {
  __builtin_amdgcn_global_load_lds((const __attribute__((address_space(1))) void*)g,
                                   (__attribute__((address_space(3))) void*)l, 16, 0, 0);
}

// v_permlane32_swap_b32 vdst,vsrc swaps vdst.hi32 <-> vsrc.lo32:
//   r[0] (new vdst) = {a.lo, b.lo}   (lane<32: a[lane];    lane>=32: b[lane-32])
//   r[1] (new vsrc) = {a.hi, b.hi}   (lane<32: a[lane+32]; lane>=32: b[lane])
// NOTE: NEVER call with a==b (same SSA value): regalloc may coalesce both operands
// into one register -> in-place half swap, both results alias (R9/R10 bug).
__device__ __forceinline__ uint2v plswap(unsigned a, unsigned b) {
  return __builtin_amdgcn_permlane32_swap(a, b, false, false);
}

// ---------------- convert x -> fp16 ----------------
__global__ void k_cvt_x(const float* __restrict__ x, _Float16* __restrict__ xh) {
  const int n4 = (4096 * 1024) / 4;
  int i = blockIdx.x * 256 + threadIdx.x;
  for (; i < n4; i += 2048 * 256) {
    float4 v = ((const float4*)x)[i];
    half4 h = { (_Float16)v.x, (_Float16)v.y, (_Float16)v.z, (_Float16)v.w };
    ((half4*)xh)[i] = h;
  }
}

// ------------- transpose+convert W (1024x1024) -> WT[n][k] fp16 -------------
__global__ void k_tw(const float* __restrict__ W0, const float* __restrict__ W1,
                     const float* __restrict__ W2, const float* __restrict__ W3,
                     _Float16* __restrict__ WT) {
  const float* W = (blockIdx.z == 0) ? W0 : (blockIdx.z == 1) ? W1 : (blockIdx.z == 2) ? W2 : W3;
  _Float16* out = WT + ((size_t)blockIdx.z << 20);
  __shared__ float t[32][33];
  const int x0 = blockIdx.x * 32;  // n
  const int y0 = blockIdx.y * 32;  // k
  const int tx = threadIdx.x, ty = threadIdx.y;  // (32,8)
#pragma unroll
  for (int r = 0; r < 4; ++r)
    t[ty + 8 * r][tx] = W[(size_t)(y0 + ty + 8 * r) * 1024 + x0 + tx];
  __syncthreads();
#pragma unroll
  for (int r = 0; r < 4; ++r)
    out[(size_t)(x0 + ty + 8 * r) * 1024 + y0 + tx] = (_Float16)t[tx][ty + 8 * r];
}

// ---------------- shared GEMM mainloop: C(128x128) = A(128xK) * B^T(128xK) ----------------
__device__ __forceinline__ void gemm_mainloop(const _Float16* __restrict__ A,
                                              const _Float16* __restrict__ Bmat,
                                              int m0, int n0,
                                              _Float16* As, _Float16* Bs,
                                              f32x4 acc[4][4]) {
  const int tid = threadIdx.x;
  const int lane = tid & 63;
  const int wid = tid >> 6;
  const int wm = wid >> 1, wn = wid & 1;
  const int c16 = lane & 15, rg = lane >> 4;

  for (int k0 = 0; k0 < 1024; k0 += 64) {
    __syncthreads();
#pragma unroll
    for (int i = 0; i < 4; ++i) {
      int e = (i * 256 + tid) * 8;       // element index within 128x64 tile
      int row = e >> 6;                  // 0..127
      int chunk = (e & 63) >> 3;         // 0..7 (16B chunk)
      int scol = ((chunk ^ (row & 7)) << 3);  // source-side swizzle (involution)
      gload_lds16(A + (size_t)(m0 + row) * 1024 + k0 + scol,
                  As + (size_t)(i * 256 + (wid << 6)) * 8);
      gload_lds16(Bmat + (size_t)(n0 + row) * 1024 + k0 + scol,
                  Bs + (size_t)(i * 256 + (wid << 6)) * 8);
    }
    __syncthreads();
#pragma unroll
    for (int kk = 0; kk < 2; ++kk) {
      half8 af[4], bfr[4];
#pragma unroll
      for (int mi = 0; mi < 4; ++mi) {
        int row = (wm << 6) + (mi << 4) + c16;
        int chunk = (kk << 2) + rg;
        af[mi] = *(const half8*)&As[(row << 6) + ((chunk ^ (row & 7)) << 3)];
      }
#pragma unroll
      for (int ni = 0; ni < 4; ++ni) {
        int row = (wn << 6) + (ni << 4) + c16;
        int chunk = (kk << 2) + rg;
        bfr[ni] = *(const half8*)&Bs[(row << 6) + ((chunk ^ (row & 7)) << 3)];
      }
#pragma unroll
      for (int mi = 0; mi < 4; ++mi)
#pragma unroll
        for (int ni = 0; ni < 4; ++ni)
          acc[mi][ni] = __builtin_amdgcn_mfma_f32_16x16x32_f16(af[mi], bfr[ni], acc[mi][ni], 0, 0, 0);
    }
  }
}

// ---------------- QKV GEMM + bias + RoPE + scatter ----------------
// Q -> [bh][t][d] scaled by (1/8)*log2(e) (exp2-domain softmax); K -> [bh][t][d];
// V -> transposed [bh][d][t]
__global__ __launch_bounds__(256, 2) void k_qkv(const _Float16* __restrict__ xh,
                                                const _Float16* __restrict__ WT,
                                                const float* __restrict__ bq,
                                                const float* __restrict__ bk,
                                                const float* __restrict__ bv,
                                                _Float16* __restrict__ Qh,
                                                _Float16* __restrict__ Kh,
                                                _Float16* __restrict__ VT) {
  __shared__ __align__(16) _Float16 As[128 * 64];
  __shared__ __align__(16) _Float16 Bs[128 * 64];
  f32x4 acc[4][4];
#pragma unroll
  for (int i = 0; i < 4; ++i)
#pragma unroll
    for (int j = 0; j < 4; ++j) acc[i][j] = (f32x4){0.f, 0.f, 0.f, 0.f};

  const int m0 = blockIdx.y * 128;
  const int ng = blockIdx.x * 128;   // 0..3071
  const int p = ng >> 10;            // 0=q,1=k,2=v
  const int n0 = ng & 1023;
  gemm_mainloop(xh, WT + ((size_t)p << 20), m0, n0, As, Bs, acc);

  const int tid = threadIdx.x, lane = tid & 63, wid = tid >> 6;
  const int wm = wid >> 1, wn = wid & 1, c16 = lane & 15, rg = lane >> 4;
  const float* bias = (p == 0) ? bq : (p == 1) ? bk : bv;
  const int nw = n0 + (wn << 6);
  const int head = nw >> 6;          // wave's 64-col strip is exactly one head
  float bi[4];
#pragma unroll
  for (int ni = 0; ni < 4; ++ni) bi[ni] = bias[nw + (ni << 4) + c16];

  if (p == 2) {  // V: store transposed [bh][d][t], vectorized half4 over t
#pragma unroll
    for (int mi = 0; mi < 4; ++mi) {
      int m = m0 + (wm << 6) + (mi << 4) + (rg << 2);
      int b = m >> 11, t0 = m & 2047;
#pragma unroll
      for (int ni = 0; ni < 4; ++ni) {
        half4 hv;
#pragma unroll
        for (int r = 0; r < 4; ++r) hv[r] = (_Float16)(acc[mi][ni][r] + bi[ni]);
        size_t base = ((size_t)(b * NH + head) * ND + (ni << 4) + c16) * NT + t0;
        *(half4*)&VT[base] = hv;
      }
    }
    return;
  }

  _Float16* Out = (p == 0) ? Qh : Kh;
  // inv_freq[c16] = 10000^(-c16/16) = 2^(-c16 * log2(10000)/16)  (accurate exp2)
  const float invf = exp2f((float)c16 * -0.8304820237218405f);
  // Q scale: (1/sqrt(64)) * log2(e)  -> S from MFMA is directly in exp2 domain
  const float qscale = (p == 0) ? 0.18033688011112042f : 1.0f;

#pragma unroll
  for (int mi = 0; mi < 4; ++mi) {
#pragma unroll
    for (int r = 0; r < 4; ++r) {
      int m = m0 + (wm << 6) + (mi << 4) + (rg << 2) + r;
      int b = m >> 11, t = m & 2047;
      float v0 = acc[mi][0][r] + bi[0];
      float v1 = acc[mi][1][r] + bi[1];
      float v2 = acc[mi][2][r] + bi[2];
      float v3 = acc[mi][3][r] + bi[3];
      {  // RoPE on d<32: pair (d, d+16)
        float th = (float)t * invf;
        float sn, cs;
        sincosf(th, &sn, &cs);   // theta reaches 2047 rad: needs libm range reduction
        float nx = v0 * cs - v1 * sn;
        v1 = v1 * cs + v0 * sn;
        v0 = nx;
      }
      size_t base = ((size_t)(b * NH + head) * NT + t) * ND;
      Out[base + 0 + c16]  = (_Float16)(v0 * qscale);
      Out[base + 16 + c16] = (_Float16)(v1 * qscale);
      Out[base + 32 + c16] = (_Float16)(v2 * qscale);
      Out[base + 48 + c16] = (_Float16)(v3 * qscale);
    }
  }
}

// ---------------- flash attention: 32x32 swapped-QK^T, LDS-free ----------------
// 512 blocks x 4 waves; wave owns 32 q-rows (q = lane&31 -> softmax state per-lane).
// QK: S^T[kv][q] = mfma32x32x16(K,Q). Row max: in-lane tree + __shfl_xor(32) (aliasing-
// safe). P repack to PV B-fragments: 4 permlane32_swap with DISTINCT operands, each
// yielding both output words. l deferred into lacc; single reduce in epilogue.
__global__ __launch_bounds__(256, 2) void k_attn(const _Float16* __restrict__ Qh,
                                                 const _Float16* __restrict__ Kh,
                                                 const _Float16* __restrict__ VT,
                                                 _Float16* __restrict__ Oh) {
  const int lin = blockIdx.x;            // 0..511
  const int xcd = lin & 7;
  const int w = lin >> 3;                // 0..63 per XCD
  const int bh = (xcd << 2) | (w & 3);   // 4 bh per XCD -> K+V 2MB in per-XCD L2
  const int tile = 15 - (w >> 2);        // descending 128-row tile length (LPT)

  const int tid = threadIdx.x, lane = tid & 63, wid = tid >> 6;  // wid 0..3
  const int q31 = lane & 31, hi = lane >> 5;
  const size_t hb = (size_t)bh * NT * ND;
  const _Float16* Qp = Qh + hb;
  const _Float16* Kp = Kh + hb;
  const _Float16* Vp = VT + hb;
  const int b = bh >> 4, h = bh & 15;

  const int q0w = (tile << 7) + (wid << 5);  // this wave's 32 q-rows
  const int qg = q0w + q31;
  const int end = q0w + 32;                  // per-wave kv extent

  half8 qf[4];
#pragma unroll
  for (int c = 0; c < 4; ++c)
    qf[c] = *(const half8*)&Qp[(size_t)qg * ND + (c << 4) + (hi << 3)];

  f32x16 oacc0, oacc1, lacc;
#pragma unroll
  for (int r = 0; r < 16; ++r) { oacc0[r] = 0.f; oacc1[r] = 0.f; lacc[r] = 0.f; }
  float m = -INFINITY;

  half8 kA[4], kB[4], vfr[4];

// K A-fragments (32 kv rows): dst[c] holds K[kt+q31][c*16 + hi*8 ..+8]
#define LOADK(dst, ktv) do {                                                    \
    const _Float16* kp_ = Kp + (size_t)((ktv) + q31) * ND + (hi << 3);          \
    dst[0] = *(const half8*)(kp_);                                              \
    dst[1] = *(const half8*)(kp_ + 16);                                         \
    dst[2] = *(const half8*)(kp_ + 32);                                         \
    dst[3] = *(const half8*)(kp_ + 48);                                         \
  } while (0)

// V A-fragments: vfr[dh*2+ks] = VT[dh*32+q31][kt + ks*16 + hi*8 ..+8]
#define LOADV(ktv) do {                                                         \
    _Pragma("unroll")                                                           \
    for (int dh = 0; dh < 2; ++dh)                                              \
      _Pragma("unroll")                                                         \
      for (int ks = 0; ks < 2; ++ks)                                            \
        vfr[dh * 2 + ks] = *(const half8*)&Vp[(size_t)((dh << 5) + q31) * NT    \
                                              + (ktv) + (ks << 4) + (hi << 3)]; \
  } while (0)

#define BODY(kb, ktc) do {                                                      \
    f32x16 s;                                                                   \
    _Pragma("unroll")                                                           \
    for (int r = 0; r < 16; ++r) s[r] = 0.f;                                    \
    __builtin_amdgcn_s_setprio(1);                                              \
    _Pragma("unroll")                                                           \
    for (int c = 0; c < 4; ++c)                                                 \
      s = __builtin_amdgcn_mfma_f32_32x32x16_f16(kb[c], qf[c], s, 0, 0, 0);     \
    __builtin_amdgcn_s_setprio(0);                                              \
    if ((ktc) + 31 > q0w) {  /* causal mask (only the last iter per wave) */    \
      int rel = qg - (ktc) - (hi << 2);                                         \
      _Pragma("unroll")                                                         \
      for (int r = 0; r < 16; ++r) {                                            \
        int crow = (r & 3) + ((r >> 2) << 3);                                   \
        if (crow > rel) s[r] = -INFINITY;                                       \
      }                                                                         \
    }                                                                           \
    /* row max: depth-4 in-lane tree + cross-half shfl_xor (aliasing-safe) */   \
    float t8[8];                                                                \
    _Pragma("unroll")                                                           \
    for (int r = 0; r < 8; ++r) t8[r] = fmaxf(s[r], s[r + 8]);                  \
    _Pragma("unroll")                                                           \
    for (int r = 0; r < 4; ++r) t8[r] = fmaxf(t8[r], t8[r + 4]);                \
    float pm = fmaxf(fmaxf(t8[0], t8[1]), fmaxf(t8[2], t8[3]));                 \
    pm = fmaxf(pm, __shfl_xor(pm, 32));                                         \
    if (!__all(pm <= m + 11.54f)) {  /* defer-max, THR=8*log2e */               \
      float mn = fmaxf(m, pm);                                                  \
      float corr = exp2f(m - mn);                                               \
      m = mn;                                                                   \
      _Pragma("unroll")                                                         \
      for (int r = 0; r < 16; ++r) {                                            \
        oacc0[r] *= corr; oacc1[r] *= corr; lacc[r] *= corr;                    \
      }                                                                         \
    }                                                                           \
    _Pragma("unroll")                                                           \
    for (int r = 0; r < 16; ++r) {                                              \
      float pv = exp2f(s[r] - m);                                               \
      s[r] = pv; lacc[r] += pv;                                                 \
    }                                                                           \
    /* pack P to fp16 words; plswap(loWord, hiWord): r[0]->frag lo word, r[1]->hi */ \
    unsigned pw0 = __builtin_bit_cast(unsigned, __builtin_amdgcn_cvt_pkrtz(s[0], s[1]));   \
    unsigned pw1 = __builtin_bit_cast(unsigned, __builtin_amdgcn_cvt_pkrtz(s[2], s[3]));   \
    unsigned pw2 = __builtin_bit_cast(unsigned, __builtin_amdgcn_cvt_pkrtz(s[4], s[5]));   \
    unsigned pw3 = __builtin_bit_cast(unsigned, __builtin_amdgcn_cvt_pkrtz(s[6], s[7]));   \
    unsigned pw4 = __builtin_bit_cast(unsigned, __builtin_amdgcn_cvt_pkrtz(s[8], s[9]));   \
    unsigned pw5 = __builtin_bit_cast(unsigned, __builtin_amdgcn_cvt_pkrtz(s[10], s[11])); \
    unsigned pw6 = __builtin_bit_cast(unsigned, __builtin_amdgcn_cvt_pkrtz(s[12], s[13])); \
    unsigned pw7 = __builtin_bit_cast(unsigned, __builtin_amdgcn_cvt_pkrtz(s[14], s[15])); \
    uint2v rA0 = plswap(pw0, pw2);  /* [0]={pw0.lo,pw2.lo}=ua.x  [1]={pw0.hi,pw2.hi}=ua.z */ \
    uint2v rA1 = plswap(pw1, pw3);  /* [0]=ua.y  [1]=ua.w */                    \
    uint2v rB0 = plswap(pw4, pw6);  /* [0]=ub.x  [1]=ub.z */                    \
    uint2v rB1 = plswap(pw5, pw7);  /* [0]=ub.y  [1]=ub.w */                    \
    uint4 ua, ub;                                                               \
    ua.x = rA0[0]; ua.y = rA1[0]; ua.z = rA0[1]; ua.w = rA1[1];                 \
    ub.x = rB0[0]; ub.y = rB1[0]; ub.z = rB0[1]; ub.w = rB1[1];                 \
    half8 pa0 = __builtin_bit_cast(half8, ua);                                  \
    half8 pa1 = __builtin_bit_cast(half8, ub);                                  \
    __builtin_amdgcn_s_setprio(1);                                              \
    oacc0 = __builtin_amdgcn_mfma_f32_32x32x16_f16(vfr[0], pa0, oacc0, 0, 0, 0); \
    oacc0 = __builtin_amdgcn_mfma_f32_32x32x16_f16(vfr[1], pa1, oacc0, 0, 0, 0); \
    oacc1 = __builtin_amdgcn_mfma_f32_32x32x16_f16(vfr[2], pa0, oacc1, 0, 0, 0); \
    oacc1 = __builtin_amdgcn_mfma_f32_32x32x16_f16(vfr[3], pa1, oacc1, 0, 0, 0); \
    __builtin_amdgcn_s_setprio(0);                                              \
  } while (0)

  // pipelined kv loop, KVBLK=32: K double-buffered, V issued at iter top;
  // sched_barrier pins the load issues above the compute (anti-sinking).
  int kt = 0;
  LOADK(kA, 0);
  for (;;) {
    LOADV(kt);
    if (kt + 32 < end) LOADK(kB, kt + 32);
    __builtin_amdgcn_sched_barrier(0);
    BODY(kA, kt);
    kt += 32;
    if (kt >= end) break;
    LOADV(kt);
    if (kt + 32 < end) LOADK(kA, kt + 32);
    __builtin_amdgcn_sched_barrier(0);
    BODY(kB, kt);
    kt += 32;
    if (kt >= end) break;
  }
#undef LOADK
#undef LOADV
#undef BODY

  // epilogue: reduce l (in-lane tree + cross-half shfl_xor), normalize, store O
  float l8[8];
#pragma unroll
  for (int r = 0; r < 8; ++r) l8[r] = lacc[r] + lacc[r + 8];
#pragma unroll
  for (int r = 0; r < 4; ++r) l8[r] = l8[r] + l8[r + 4];
  float ls = (l8[0] + l8[1]) + (l8[2] + l8[3]);
  ls += __shfl_xor(ls, 32);
  float il = 1.f / ls;
  size_t obase = ((size_t)b * NT + qg) * NC + h * ND;
#pragma unroll
  for (int g = 0; g < 4; ++g) {
    int d0 = (g << 3) + (hi << 2);
    half4 h4, h5;
#pragma unroll
    for (int r = 0; r < 4; ++r) {
      h4[r] = (_Float16)(oacc0[(g << 2) + r] * il);
      h5[r] = (_Float16)(oacc1[(g << 2) + r] * il);
    }
    *(half4*)&Oh[obase + d0] = h4;
    *(half4*)&Oh[obase + 32 + d0] = h5;
  }
}

// ---------------- output projection GEMM (fp32 out + bias) ----------------
__global__ __launch_bounds__(256, 2) void k_out(const _Float16* __restrict__ Oh,
                                                const _Float16* __restrict__ WoT,
                                                const float* __restrict__ bo,
                                                float* __restrict__ out) {
  __shared__ __align__(16) _Float16 As[128 * 64];
  __shared__ __align__(16) _Float16 Bs[128 * 64];
  f32x4 acc[4][4];
#pragma unroll
  for (int i = 0; i < 4; ++i)
#pragma unroll
    for (int j = 0; j < 4; ++j) acc[i][j] = (f32x4){0.f, 0.f, 0.f, 0.f};

  const int m0 = blockIdx.y * 128;
  const int n0 = blockIdx.x * 128;
  gemm_mainloop(Oh, WoT, m0, n0, As, Bs, acc);

  const int tid = threadIdx.x, lane = tid & 63, wid = tid >> 6;
  const int wm = wid >> 1, wn = wid & 1, c16 = lane & 15, rg = lane >> 4;
  float bi[4];
#pragma unroll
  for (int ni = 0; ni < 4; ++ni) bi[ni] = bo[n0 + (wn << 6) + (ni << 4) + c16];
#pragma unroll
  for (int mi = 0; mi < 4; ++mi) {
#pragma unroll
    for (int r = 0; r < 4; ++r) {
      int m = m0 + (wm << 6) + (mi << 4) + (rg << 2) + r;
#pragma unroll
      for (int ni = 0; ni < 4; ++ni) {
        int n = n0 + (wn << 6) + (ni << 4) + c16;
        out[(size_t)m * NC + n] = acc[mi][ni][r] + bi[ni];
      }
    }
  }
}

extern "C" void kernel_launch(void* const* d_in, const int* in_sizes, int n_in,
                              void* d_out, int out_size, void* d_ws, size_t ws_size,
                              hipStream_t stream) {
  const float* x  = (const float*)d_in[0];
  const float* Wq = (const float*)d_in[1];
  const float* bq = (const float*)d_in[2];
  const float* Wk = (const float*)d_in[3];
  const float* bk = (const float*)d_in[4];
  const float* Wv = (const float*)d_in[5];
  const float* bv = (const float*)d_in[6];
  const float* Wo = (const float*)d_in[7];
  const float* bo = (const float*)d_in[8];
  float* out = (float*)d_out;

  char* ws = (char*)d_ws;
  _Float16* xh = (_Float16*)ws;                       // 8 MB  [4096][1024]
  _Float16* WT = (_Float16*)(ws + (8ull << 20));      // 8 MB  [4][1024][1024] n-major
  _Float16* Qh = (_Float16*)(ws + (16ull << 20));     // 8 MB  [32][2048][64]
  _Float16* Kh = (_Float16*)(ws + (24ull << 20));     // 8 MB  [32][2048][64]
  _Float16* Vt = (_Float16*)(ws + (32ull << 20));     // 8 MB  [32][64][2048] (transposed)
  _Float16* Oh = (_Float16*)(ws + (40ull << 20));     // 8 MB  [4096][1024]

  k_cvt_x<<<2048, 256, 0, stream>>>(x, xh);
  k_tw<<<dim3(32, 32, 4), dim3(32, 8), 0, stream>>>(Wq, Wk, Wv, Wo, WT);
  k_qkv<<<dim3(24, 32), 256, 0, stream>>>(xh, WT, bq, bk, bv, Qh, Kh, Vt);
  k_attn<<<512, 256, 0, stream>>>(Qh, Kh, Vt, Oh);
  k_out<<<dim3(8, 32), 256, 0, stream>>>(Oh, WT + (3ull << 20), bo, out);
}